// Round 4
// baseline (152.709 us; speedup 1.0000x reference)
//
#include <hip/hip_runtime.h>
#include <cfloat>

typedef unsigned short u16;
typedef u16   u16x4 __attribute__((ext_vector_type(4)));
typedef float f32x4 __attribute__((ext_vector_type(4)));
typedef _Float16 f16x8 __attribute__((ext_vector_type(8)));

#define GL2LDS(gp, lp) __builtin_amdgcn_global_load_lds(                      \
    (const __attribute__((address_space(1))) void*)(gp),                      \
    (__attribute__((address_space(3))) void*)(lp), 16, 0, 0)

static __device__ __forceinline__ void fence_barrier() {
  asm volatile("" ::: "memory");
  __builtin_amdgcn_s_barrier();
  asm volatile("" ::: "memory");
}

__device__ __forceinline__ void f32_to_f16pair(float f, u16& hi, u16& lo) {
  _Float16 h = (_Float16)f;               // RNE
  _Float16 l = (_Float16)(f - (float)h);  // residual (exact subtraction)
  hi = __builtin_bit_cast(u16, h);
  lo = __builtin_bit_cast(u16, l);
}

// Pretile a [R,512] fp32 matrix into f16 hi/lo panels.
// Panel unit: (tile of 256 rows, K-step s of 32 cols) = 32768 bytes.
// Row layout inside a unit: 128 B = [hi: 32 f16 | lo: 32 f16], byte offset
// XOR-swizzled with ((r&7)<<4) — exact LDS image for linear global_load_lds.
__global__ __launch_bounds__(128) void vq_prep(
    const float* __restrict__ src, u16* __restrict__ pan,
    float* __restrict__ sq, float* __restrict__ copy_out) {
  __shared__ float red[2];
  const int row_g = blockIdx.x;
  const int t = threadIdx.x;             // 0..127, 4 floats each
  float4 v = reinterpret_cast<const float4*>(src + (size_t)row_g * 512)[t];
  if (copy_out)
    reinterpret_cast<float4*>(copy_out + (size_t)row_g * 512)[t] = v;
  u16 hi[4], lo[4];
  float f[4] = {v.x, v.y, v.z, v.w};
  #pragma unroll
  for (int i = 0; i < 4; ++i) f32_to_f16pair(f[i], hi[i], lo[i]);
  const int d = t * 4;
  const int tile = row_g >> 8, r = row_g & 255;
  const int s = d >> 5, c = d & 31;
  const size_t pbase = ((size_t)tile * 16 + s) * 32768;
  const unsigned swz = ((unsigned)(r & 7)) << 4;
  const unsigned bh = ((unsigned)(r * 128 + c * 2)) ^ swz;
  const unsigned bl = ((unsigned)(r * 128 + 64 + c * 2)) ^ swz;
  u16x4 th = {hi[0], hi[1], hi[2], hi[3]};
  u16x4 tl = {lo[0], lo[1], lo[2], lo[3]};
  *reinterpret_cast<u16x4*>((char*)pan + pbase + bh) = th;
  *reinterpret_cast<u16x4*>((char*)pan + pbase + bl) = tl;
  if (sq) {
    float ssum = v.x*v.x + v.y*v.y + v.z*v.z + v.w*v.w;
    #pragma unroll
    for (int m = 1; m < 64; m <<= 1) ssum += __shfl_xor(ssum, m);
    if ((t & 63) == 0) red[t >> 6] = ssum;
    __syncthreads();
    if (t == 0) sq[row_g] = red[0] + red[1];
  }
}

// Distance GEMM + per-tile argmin. Tile 256x256, BK=32, 8 waves (2x4).
// Quadrant phases with frag pipelining + counted vmcnt (T3+T4+T5 port):
//   p0: rd B-h1        | stage A-h0'  | Q(0,0)=A0*B0 |  (no vmcnt)
//   p1: -              | stage B-h0'  | Q(0,1)=A0*B1 | vmcnt(4)
//   p2: rd A-h1        | stage B-h1'  | Q(1,0)=A1*B0 | vmcnt(2)
//   p3: rd A0',B0'@nxt | stage A-h1'  | Q(1,1)=A1*B1 | vmcnt(2)
// Row mapping rh*128+wm*64 / col mapping ch*128+wn*32 keeps each quadrant's
// operands inside one contiguous 16KB stage half-unit.
template <int INLINE_A>
__global__ __launch_bounds__(512, 2) void vq_gemm(
    const float* __restrict__ X,
    const u16* __restrict__ Apan, const u16* __restrict__ Bpan,
    const float* __restrict__ c2,
    float2* __restrict__ part, int nnt) {
  __shared__ u16 sA[2][16384], sB[2][16384];   // 2 x 32 KiB each
  const int tid = threadIdx.x;
  const int lane = tid & 63, wid = tid >> 6;   // 8 waves
  const int wm = wid >> 2, wn = wid & 3;       // 2 x 4
  const int nwg = gridDim.x;
  const int bid = blockIdx.x;
  const int swb = (bid & 7) * (nwg >> 3) + (bid >> 3);
  const int mtile = swb / nnt, ntile = swb % nnt;
  const int lrow = lane & 15, kgrp = lane >> 4;
  f32x4 acc[8][4] = {};

  auto stageA = [&](int s, int buf, int half) {
    const char* g = (const char*)Apan + ((size_t)mtile * 16 + s) * 32768 + half * 16384;
    #pragma unroll
    for (int i = 0; i < 2; ++i) {
      const int off = i * 8192 + wid * 1024;
      GL2LDS(g + off + lane * 16, (char*)sA[buf] + half * 16384 + off);
    }
  };
  auto stageB = [&](int s, int buf, int half) {
    const char* g = (const char*)Bpan + ((size_t)ntile * 16 + s) * 32768 + half * 16384;
    #pragma unroll
    for (int i = 0; i < 2; ++i) {
      const int off = i * 8192 + wid * 1024;
      GL2LDS(g + off + lane * 16, (char*)sB[buf] + half * 16384 + off);
    }
  };
  auto inlineA = [&](int s, int buf) {   // fallback: convert X tile into LDS
    const float* ga = X + ((size_t)mtile * 256) * 512 + s * 32;
    #pragma unroll
    for (int p = 0; p < 4; ++p) {
      const int cch = tid + p * 512;
      const int r = cch >> 3, c0 = (cch & 7) * 4;
      float4 v = *reinterpret_cast<const float4*>(ga + (size_t)r * 512 + c0);
      u16 hi[4], lo[4];
      float f[4] = {v.x, v.y, v.z, v.w};
      #pragma unroll
      for (int i2 = 0; i2 < 4; ++i2) f32_to_f16pair(f[i2], hi[i2], lo[i2]);
      const unsigned swz = ((unsigned)(r & 7)) << 4;
      const unsigned bh = ((unsigned)(r * 128 + c0 * 2)) ^ swz;
      const unsigned bl = ((unsigned)(r * 128 + 64 + c0 * 2)) ^ swz;
      u16x4 th = {hi[0], hi[1], hi[2], hi[3]};
      u16x4 tl = {lo[0], lo[1], lo[2], lo[3]};
      *reinterpret_cast<u16x4*>((char*)sA[buf] + bh) = th;
      *reinterpret_cast<u16x4*>((char*)sA[buf] + bl) = tl;
    }
  };

  f16x8 a0h[4], a0l[4], a1h[4], a1l[4];
  f16x8 b0h[2], b0l[2], b1h[2], b1l[2];

  auto readA = [&](int buf, int rh, f16x8* h, f16x8* l) {
    #pragma unroll
    for (int t = 0; t < 4; ++t) {
      const int ar = rh * 128 + wm * 64 + t * 16 + lrow;
      const unsigned swz = ((unsigned)(ar & 7)) << 4;
      const unsigned a0 = (unsigned)(ar * 128 + kgrp * 16);
      h[t] = *reinterpret_cast<const f16x8*>((const char*)sA[buf] + (a0 ^ swz));
      l[t] = *reinterpret_cast<const f16x8*>((const char*)sA[buf] + ((a0 + 64) ^ swz));
    }
  };
  auto readB = [&](int buf, int ch, f16x8* h, f16x8* l) {
    #pragma unroll
    for (int u = 0; u < 2; ++u) {
      const int br = ch * 128 + wn * 32 + u * 16 + lrow;
      const unsigned swz = ((unsigned)(br & 7)) << 4;
      const unsigned b0 = (unsigned)(br * 128 + kgrp * 16);
      h[u] = *reinterpret_cast<const f16x8*>((const char*)sB[buf] + (b0 ^ swz));
      l[u] = *reinterpret_cast<const f16x8*>((const char*)sB[buf] + ((b0 + 64) ^ swz));
    }
  };
  auto mfmaQ = [&](const f16x8* ah, const f16x8* al,
                   const f16x8* bh, const f16x8* bl, int rh, int ch) {
    __builtin_amdgcn_s_setprio(1);
    #pragma unroll
    for (int t = 0; t < 4; ++t) {
      const int i = rh * 4 + t;
      #pragma unroll
      for (int u = 0; u < 2; ++u) {
        const int j = ch * 2 + u;
        acc[i][j] = __builtin_amdgcn_mfma_f32_16x16x32_f16(ah[t], bh[u], acc[i][j], 0, 0, 0);
        acc[i][j] = __builtin_amdgcn_mfma_f32_16x16x32_f16(ah[t], bl[u], acc[i][j], 0, 0, 0);
        acc[i][j] = __builtin_amdgcn_mfma_f32_16x16x32_f16(al[t], bh[u], acc[i][j], 0, 0, 0);
      }
    }
    __builtin_amdgcn_s_setprio(0);
  };

  // ---- prologue: stage step 0 fully, drain once, read first frags
  stageB(0, 0, 0); stageB(0, 0, 1);
  if constexpr (INLINE_A) inlineA(0, 0);
  else { stageA(0, 0, 0); stageA(0, 0, 1); }
  asm volatile("s_waitcnt vmcnt(0) lgkmcnt(0)" ::: "memory");
  __builtin_amdgcn_s_barrier();
  asm volatile("" ::: "memory");
  readA(0, 0, a0h, a0l);
  readB(0, 0, b0h, b0l);

  int cur = 0;
  for (int s = 0; s < 16; ++s) {
    const int nxt = cur ^ 1;
    const bool more = (s + 1 < 16);
    // ---------------- p0
    readB(cur, 1, b1h, b1l);                       // frags for p1
    if (more) { if constexpr (!INLINE_A) stageA(s + 1, nxt, 0); }
    fence_barrier();
    mfmaQ(a0h, a0l, b0h, b0l, 0, 0);
    fence_barrier();
    // ---------------- p1
    if (more) {
      stageB(s + 1, nxt, 0);
      if constexpr (INLINE_A) {
        inlineA(s + 1, nxt);
        asm volatile("s_waitcnt lgkmcnt(0)" ::: "memory");
      }
    }
    fence_barrier();
    mfmaQ(a0h, a0l, b1h, b1l, 0, 1);
    asm volatile("s_waitcnt vmcnt(4)" ::: "memory");
    fence_barrier();
    // ---------------- p2
    readA(cur, 1, a1h, a1l);                       // frags for this phase
    if (more) stageB(s + 1, nxt, 1);
    fence_barrier();
    mfmaQ(a1h, a1l, b0h, b0l, 1, 0);
    asm volatile("s_waitcnt vmcnt(2)" ::: "memory");
    fence_barrier();
    // ---------------- p3
    if (more) {
      readA(nxt, 0, a0h, a0l);                     // frags for p0(s+1)
      readB(nxt, 0, b0h, b0l);
      if constexpr (!INLINE_A) stageA(s + 1, nxt, 1);
    }
    fence_barrier();
    mfmaQ(a1h, a1l, b1h, b1l, 1, 1);
    if constexpr (INLINE_A)
      asm volatile("s_waitcnt vmcnt(0)" ::: "memory");
    else
      asm volatile("s_waitcnt vmcnt(2)" ::: "memory");
    fence_barrier();
    cur ^= 1;
  }

  // ---- epilogue: per-row argmin over this wave's 8 col-tiles
  float c2v[4];
  #pragma unroll
  for (int j = 0; j < 4; ++j)
    c2v[j] = c2[ntile * 256 + (j >> 1) * 128 + wn * 32 + (j & 1) * 16 + lrow];
  #pragma unroll
  for (int i = 0; i < 8; ++i) {
    #pragma unroll
    for (int jj = 0; jj < 4; ++jj) {
      float v = FLT_MAX; int idx = 0x7fffffff;
      #pragma unroll
      for (int j = 0; j < 4; ++j) {
        const float sc = c2v[j] - 2.0f * acc[i][j][jj];
        const int col = ntile * 256 + (j >> 1) * 128 + wn * 32 + (j & 1) * 16 + lrow;
        if (sc < v || (sc == v && col < idx)) { v = sc; idx = col; }
      }
      #pragma unroll
      for (int m = 1; m < 16; m <<= 1) {
        const float ov = __shfl_xor(v, m);
        const int oi = __shfl_xor(idx, m);
        if (ov < v || (ov == v && oi < idx)) { v = ov; idx = oi; }
      }
      if (lrow == 0) {
        const int row = mtile * 256 + (i >> 2) * 128 + wm * 64 + (i & 3) * 16 + kgrp * 4 + jj;
        part[(size_t)row * 32 + (ntile * 4 + wn)] =
            make_float2(v, __int_as_float(idx));
      }
    }
  }
}

// Final: reduce 32 partials per row, gather codebook row, write outputs.
__global__ __launch_bounds__(256) void vq_final(
    const float* __restrict__ X, const float* __restrict__ CB,
    const float2* __restrict__ part,
    float* __restrict__ out0, float* __restrict__ out1, float* __restrict__ out2,
    int nsub) {
  const int row = blockIdx.x * 4 + (threadIdx.x >> 6);
  const int l = threadIdx.x & 63;
  float v = FLT_MAX; int idx = 0x7fffffff;
  for (int i = l; i < nsub; i += 64) {
    const float2 p = part[(size_t)row * nsub + i];
    const int pi = __float_as_int(p.y);
    if (p.x < v || (p.x == v && pi < idx)) { v = p.x; idx = pi; }
  }
  #pragma unroll
  for (int m = 1; m < 64; m <<= 1) {
    const float ov = __shfl_xor(v, m);
    const int oi = __shfl_xor(idx, m);
    if (ov < v || (ov == v && oi < idx)) { v = ov; idx = oi; }
  }
  const float4* xr = reinterpret_cast<const float4*>(X + (size_t)row * 512);
  const float4* cr = reinterpret_cast<const float4*>(CB + (size_t)idx * 512);
  float4* q  = reinterpret_cast<float4*>(out0 + (size_t)row * 512);
  float4* ls = reinterpret_cast<float4*>(out1 + (size_t)row * 512);
  #pragma unroll
  for (int p = 0; p < 2; ++p) {
    const int e = l + 64 * p;
    const float4 xv = xr[e], cv = cr[e];
    float4 d4, qv, lv;
    d4.x = cv.x - xv.x; d4.y = cv.y - xv.y; d4.z = cv.z - xv.z; d4.w = cv.w - xv.w;
    qv.x = xv.x + d4.x; qv.y = xv.y + d4.y; qv.z = xv.z + d4.z; qv.w = xv.w + d4.w;
    lv.x = d4.x * d4.x; lv.y = d4.y * d4.y; lv.z = d4.z * d4.z; lv.w = d4.w * d4.w;
    q[e] = qv; ls[e] = lv;
  }
  if (l == 0) out2[row] = (float)idx;
}

extern "C" void kernel_launch(void* const* d_in, const int* in_sizes, int n_in,
                              void* d_out, int out_size, void* d_ws, size_t ws_size,
                              hipStream_t stream) {
  const float* X  = (const float*)d_in[0];   // [M,512] fp32
  const float* CB = (const float*)d_in[1];   // [K,512] fp32
  const int D = 512;
  const int M = in_sizes[0] / D;             // 16384
  const int K = in_sizes[1] / D;             // 2048
  float* out0 = (float*)d_out;               // quantized_ste [M,512]
  float* out1 = out0 + (size_t)M * D;        // loss          [M,512]
  float* out2 = out1 + (size_t)M * D;        // nn_idx (as f32) [M]
  float* out3 = out2 + M;                    // codebook copy [K,512]

  char* ws = (char*)d_ws;
  size_t off = 0;
  u16* Bpan = (u16*)(ws + off); off += (size_t)K * D * 4;     // hi+lo interleaved
  float* c2 = (float*)(ws + off); off += (size_t)K * 4;
  const int nsub = K / 64;                                    // 32
  float2* part = (float2*)(ws + off); off += (size_t)M * nsub * 8;
  u16* Apan = (u16*)(ws + off);
  const size_t need_big = off + (size_t)M * D * 4;
  const bool big = (ws_size >= need_big);

  vq_prep<<<K, 128, 0, stream>>>(CB, Bpan, c2, out3);
  const int nmt = M / 256, nnt = K / 256;
  const int nwg = nmt * nnt;                                  // 512
  if (big) {
    vq_prep<<<M, 128, 0, stream>>>(X, Apan, nullptr, nullptr);
    vq_gemm<0><<<nwg, 512, 0, stream>>>(X, Apan, Bpan, c2, part, nnt);
  } else {
    vq_gemm<1><<<nwg, 512, 0, stream>>>(X, nullptr, Bpan, c2, part, nnt);
  }
  vq_final<<<M / 4, 256, 0, stream>>>(X, CB, part, out0, out1, out2, nsub);
}

// Round 5
// 146.727 us; speedup vs baseline: 1.0408x; 1.0408x over previous
//
#include <hip/hip_runtime.h>
#include <cfloat>

typedef unsigned short u16;
typedef u16   u16x4 __attribute__((ext_vector_type(4)));
typedef float f32x4 __attribute__((ext_vector_type(4)));
typedef _Float16 f16x8 __attribute__((ext_vector_type(8)));

#define GL2LDS(gp, lp) __builtin_amdgcn_global_load_lds(                      \
    (const __attribute__((address_space(1))) void*)(gp),                      \
    (__attribute__((address_space(3))) void*)(lp), 16, 0, 0)

__device__ __forceinline__ void f32_to_f16pair(float f, u16& hi, u16& lo) {
  _Float16 h = (_Float16)f;               // RNE
  _Float16 l = (_Float16)(f - (float)h);  // residual (exact subtraction)
  hi = __builtin_bit_cast(u16, h);
  lo = __builtin_bit_cast(u16, l);
}

// Pretile a [R,512] fp32 matrix into f16 hi/lo panels.
// Panel unit: (tile of 256 rows, K-step s of 32 cols) = 32768 bytes.
// Row layout inside a unit: 128 B = [hi: 32 f16 | lo: 32 f16], byte offset
// XOR-swizzled with ((r&7)<<4) — exact LDS image for linear global_load_lds.
__global__ __launch_bounds__(128) void vq_prep(
    const float* __restrict__ src, u16* __restrict__ pan,
    float* __restrict__ sq, float* __restrict__ copy_out) {
  __shared__ float red[2];
  const int row_g = blockIdx.x;
  const int t = threadIdx.x;             // 0..127, 4 floats each
  float4 v = reinterpret_cast<const float4*>(src + (size_t)row_g * 512)[t];
  if (copy_out)
    reinterpret_cast<float4*>(copy_out + (size_t)row_g * 512)[t] = v;
  u16 hi[4], lo[4];
  float f[4] = {v.x, v.y, v.z, v.w};
  #pragma unroll
  for (int i = 0; i < 4; ++i) f32_to_f16pair(f[i], hi[i], lo[i]);
  const int d = t * 4;
  const int tile = row_g >> 8, r = row_g & 255;
  const int s = d >> 5, c = d & 31;
  const size_t pbase = ((size_t)tile * 16 + s) * 32768;
  const unsigned swz = ((unsigned)(r & 7)) << 4;
  const unsigned bh = ((unsigned)(r * 128 + c * 2)) ^ swz;
  const unsigned bl = ((unsigned)(r * 128 + 64 + c * 2)) ^ swz;
  u16x4 th = {hi[0], hi[1], hi[2], hi[3]};
  u16x4 tl = {lo[0], lo[1], lo[2], lo[3]};
  *reinterpret_cast<u16x4*>((char*)pan + pbase + bh) = th;
  *reinterpret_cast<u16x4*>((char*)pan + pbase + bl) = tl;
  if (sq) {
    float ssum = v.x*v.x + v.y*v.y + v.z*v.z + v.w*v.w;
    #pragma unroll
    for (int m = 1; m < 64; m <<= 1) ssum += __shfl_xor(ssum, m);
    if ((t & 63) == 0) red[t >> 6] = ssum;
    __syncthreads();
    if (t == 0) sq[row_g] = red[0] + red[1];
  }
}

// Distance GEMM + per-tile argmin. Tile 256x256, BK=32, 8 waves (2x4),
// per-wave 128x64. m201-faithful phases: per K-step, 4 quadrant phases
//   p: { ds_read THIS phase's frags | stage one 16KB half-tile (2 gl2lds)
//        | s_barrier | lgkmcnt(0) | setprio(1) 24 MFMA setprio(0)
//        | [vmcnt(4) at p0/p1/p3] | s_barrier }
// Stage order A-h0',B-h0',B-h1',A-h1' mirrors consumption; vmcnt(4) gives
// every half-tile a >=3-phase flight window (never drained to 0 in loop).
template <int INLINE_A>
__global__ __launch_bounds__(512, 2) void vq_gemm(
    const float* __restrict__ X,
    const u16* __restrict__ Apan, const u16* __restrict__ Bpan,
    const float* __restrict__ c2,
    float2* __restrict__ part, int nnt) {
  __shared__ u16 sA0[16384], sA1[16384], sB0[16384], sB1[16384];
  const int tid = threadIdx.x;
  const int lane = tid & 63, wid = tid >> 6;   // 8 waves
  const int wm = wid >> 2, wn = wid & 3;       // 2 x 4
  const int nwg = gridDim.x;
  const int bid = blockIdx.x;
  const int swb = (bid & 7) * (nwg >> 3) + (bid >> 3);
  const int mtile = swb / nnt, ntile = swb % nnt;
  const int lrow = lane & 15, kgrp = lane >> 4;
  f32x4 acc[8][4] = {};

  auto stageHalfA = [&](u16* dst, int s, int half) {
    const char* g = (const char*)Apan + ((size_t)mtile * 16 + s) * 32768 + half * 16384;
    #pragma unroll
    for (int i = 0; i < 2; ++i) {
      const int off = i * 8192 + wid * 1024;
      GL2LDS(g + off + lane * 16, (char*)dst + half * 16384 + off);
    }
  };
  auto stageHalfB = [&](u16* dst, int s, int half) {
    const char* g = (const char*)Bpan + ((size_t)ntile * 16 + s) * 32768 + half * 16384;
    #pragma unroll
    for (int i = 0; i < 2; ++i) {
      const int off = i * 8192 + wid * 1024;
      GL2LDS(g + off + lane * 16, (char*)dst + half * 16384 + off);
    }
  };
  auto inlineA = [&](u16* dst, int s) {     // fallback: convert X tile into LDS
    const float* ga = X + ((size_t)mtile * 256) * 512 + s * 32;
    #pragma unroll
    for (int p = 0; p < 4; ++p) {
      const int cch = tid + p * 512;
      const int r = cch >> 3, c0 = (cch & 7) * 4;
      float4 v = *reinterpret_cast<const float4*>(ga + (size_t)r * 512 + c0);
      u16 hi[4], lo[4];
      float f[4] = {v.x, v.y, v.z, v.w};
      #pragma unroll
      for (int i2 = 0; i2 < 4; ++i2) f32_to_f16pair(f[i2], hi[i2], lo[i2]);
      const unsigned swz = ((unsigned)(r & 7)) << 4;
      const unsigned bh = ((unsigned)(r * 128 + c0 * 2)) ^ swz;
      const unsigned bl = ((unsigned)(r * 128 + 64 + c0 * 2)) ^ swz;
      u16x4 th = {hi[0], hi[1], hi[2], hi[3]};
      u16x4 tl = {lo[0], lo[1], lo[2], lo[3]};
      *reinterpret_cast<u16x4*>((char*)dst + bh) = th;
      *reinterpret_cast<u16x4*>((char*)dst + bl) = tl;
    }
  };

  f16x8 a0h[4], a0l[4], a1h[4], a1l[4];
  f16x8 b0h[2], b0l[2], b1h[2], b1l[2];

  auto readA = [&](const u16* buf, int rh, f16x8* h, f16x8* l) {
    #pragma unroll
    for (int t = 0; t < 4; ++t) {
      const int ar = rh * 128 + wm * 64 + t * 16 + lrow;
      const unsigned swz = ((unsigned)(ar & 7)) << 4;
      const unsigned a0 = (unsigned)(ar * 128 + kgrp * 16);
      h[t] = *reinterpret_cast<const f16x8*>((const char*)buf + (a0 ^ swz));
      l[t] = *reinterpret_cast<const f16x8*>((const char*)buf + ((a0 + 64) ^ swz));
    }
  };
  auto readB = [&](const u16* buf, int ch, f16x8* h, f16x8* l) {
    #pragma unroll
    for (int u = 0; u < 2; ++u) {
      const int br = ch * 128 + wn * 32 + u * 16 + lrow;
      const unsigned swz = ((unsigned)(br & 7)) << 4;
      const unsigned b0 = (unsigned)(br * 128 + kgrp * 16);
      h[u] = *reinterpret_cast<const f16x8*>((const char*)buf + (b0 ^ swz));
      l[u] = *reinterpret_cast<const f16x8*>((const char*)buf + ((b0 + 64) ^ swz));
    }
  };
  auto mfmaQ = [&](const f16x8* ah, const f16x8* al,
                   const f16x8* bh, const f16x8* bl, int rh, int ch) {
    __builtin_amdgcn_s_setprio(1);
    #pragma unroll
    for (int t = 0; t < 4; ++t) {
      const int i = rh * 4 + t;
      #pragma unroll
      for (int u = 0; u < 2; ++u) {
        const int j = ch * 2 + u;
        acc[i][j] = __builtin_amdgcn_mfma_f32_16x16x32_f16(ah[t], bh[u], acc[i][j], 0, 0, 0);
        acc[i][j] = __builtin_amdgcn_mfma_f32_16x16x32_f16(ah[t], bl[u], acc[i][j], 0, 0, 0);
        acc[i][j] = __builtin_amdgcn_mfma_f32_16x16x32_f16(al[t], bh[u], acc[i][j], 0, 0, 0);
      }
    }
    __builtin_amdgcn_s_setprio(0);
  };

  #define MEMFENCE asm volatile("" ::: "memory")
  #define BAR      do { MEMFENCE; __builtin_amdgcn_s_barrier(); MEMFENCE; } while (0)
  #define LGKM0    do { asm volatile("s_waitcnt lgkmcnt(0)" ::: "memory");    \
                        __builtin_amdgcn_sched_barrier(0); } while (0)
  #define VM4      asm volatile("s_waitcnt vmcnt(4)" ::: "memory")

  auto kstep = [&](const u16* Ac, const u16* Bc, u16* An, u16* Bn,
                   int s, bool more) {
    // ---------------- p0 : Q(0,0)   [stage A-h0']
    readA(Ac, 0, a0h, a0l);
    readB(Bc, 0, b0h, b0l);
    MEMFENCE;
    if (more) { if constexpr (INLINE_A) inlineA(An, s + 1); else stageHalfA(An, s + 1, 0); }
    BAR; LGKM0;
    mfmaQ(a0h, a0l, b0h, b0l, 0, 0);
    VM4; BAR;
    // ---------------- p1 : Q(0,1)   [stage B-h0']
    readB(Bc, 1, b1h, b1l);
    MEMFENCE;
    if (more) stageHalfB(Bn, s + 1, 0);
    BAR; LGKM0;
    mfmaQ(a0h, a0l, b1h, b1l, 0, 1);
    VM4; BAR;
    // ---------------- p2 : Q(1,0)   [stage B-h1']
    readA(Ac, 1, a1h, a1l);
    MEMFENCE;
    if (more) stageHalfB(Bn, s + 1, 1);
    BAR; LGKM0;
    mfmaQ(a1h, a1l, b0h, b0l, 1, 0);
    BAR;
    // ---------------- p3 : Q(1,1)   [stage A-h1']
    if (more) { if constexpr (!INLINE_A) stageHalfA(An, s + 1, 1); }
    BAR; LGKM0;
    mfmaQ(a1h, a1l, b1h, b1l, 1, 1);
    VM4; BAR;
  };

  // ---- prologue: stage step 0 fully, drain once
  if constexpr (INLINE_A) inlineA(sA0, 0); else { stageHalfA(sA0, 0, 0); stageHalfA(sA0, 0, 1); }
  stageHalfB(sB0, 0, 0); stageHalfB(sB0, 0, 1);
  asm volatile("s_waitcnt vmcnt(0) lgkmcnt(0)" ::: "memory");
  BAR;

  #pragma unroll 1
  for (int it = 0; it < 8; ++it) {
    kstep(sA0, sB0, sA1, sB1, it * 2, true);
    kstep(sA1, sB1, sA0, sB0, it * 2 + 1, it < 7);
  }

  #undef MEMFENCE
  #undef BAR
  #undef LGKM0
  #undef VM4

  // ---- epilogue: per-row argmin over this wave's 8 col-tiles
  float c2v[4];
  #pragma unroll
  for (int j = 0; j < 4; ++j)
    c2v[j] = c2[ntile * 256 + (j >> 1) * 128 + wn * 32 + (j & 1) * 16 + lrow];
  #pragma unroll
  for (int i = 0; i < 8; ++i) {
    #pragma unroll
    for (int jj = 0; jj < 4; ++jj) {
      float v = FLT_MAX; int idx = 0x7fffffff;
      #pragma unroll
      for (int j = 0; j < 4; ++j) {
        const float sc = c2v[j] - 2.0f * acc[i][j][jj];
        const int col = ntile * 256 + (j >> 1) * 128 + wn * 32 + (j & 1) * 16 + lrow;
        if (sc < v || (sc == v && col < idx)) { v = sc; idx = col; }
      }
      #pragma unroll
      for (int m = 1; m < 16; m <<= 1) {
        const float ov = __shfl_xor(v, m);
        const int oi = __shfl_xor(idx, m);
        if (ov < v || (ov == v && oi < idx)) { v = ov; idx = oi; }
      }
      if (lrow == 0) {
        const int row = mtile * 256 + (i >> 2) * 128 + wm * 64 + (i & 3) * 16 + kgrp * 4 + jj;
        part[(size_t)row * 32 + (ntile * 4 + wn)] =
            make_float2(v, __int_as_float(idx));
      }
    }
  }
}

// Final: reduce 32 partials per row, gather codebook row, write outputs.
__global__ __launch_bounds__(256) void vq_final(
    const float* __restrict__ X, const float* __restrict__ CB,
    const float2* __restrict__ part,
    float* __restrict__ out0, float* __restrict__ out1, float* __restrict__ out2,
    int nsub) {
  const int row = blockIdx.x * 4 + (threadIdx.x >> 6);
  const int l = threadIdx.x & 63;
  float v = FLT_MAX; int idx = 0x7fffffff;
  for (int i = l; i < nsub; i += 64) {
    const float2 p = part[(size_t)row * nsub + i];
    const int pi = __float_as_int(p.y);
    if (p.x < v || (p.x == v && pi < idx)) { v = p.x; idx = pi; }
  }
  #pragma unroll
  for (int m = 1; m < 64; m <<= 1) {
    const float ov = __shfl_xor(v, m);
    const int oi = __shfl_xor(idx, m);
    if (ov < v || (ov == v && oi < idx)) { v = ov; idx = oi; }
  }
  const float4* xr = reinterpret_cast<const float4*>(X + (size_t)row * 512);
  const float4* cr = reinterpret_cast<const float4*>(CB + (size_t)idx * 512);
  float4* q  = reinterpret_cast<float4*>(out0 + (size_t)row * 512);
  float4* ls = reinterpret_cast<float4*>(out1 + (size_t)row * 512);
  #pragma unroll
  for (int p = 0; p < 2; ++p) {
    const int e = l + 64 * p;
    const float4 xv = xr[e], cv = cr[e];
    float4 d4, qv, lv;
    d4.x = cv.x - xv.x; d4.y = cv.y - xv.y; d4.z = cv.z - xv.z; d4.w = cv.w - xv.w;
    qv.x = xv.x + d4.x; qv.y = xv.y + d4.y; qv.z = xv.z + d4.z; qv.w = xv.w + d4.w;
    lv.x = d4.x * d4.x; lv.y = d4.y * d4.y; lv.z = d4.z * d4.z; lv.w = d4.w * d4.w;
    q[e] = qv; ls[e] = lv;
  }
  if (l == 0) out2[row] = (float)idx;
}

extern "C" void kernel_launch(void* const* d_in, const int* in_sizes, int n_in,
                              void* d_out, int out_size, void* d_ws, size_t ws_size,
                              hipStream_t stream) {
  const float* X  = (const float*)d_in[0];   // [M,512] fp32
  const float* CB = (const float*)d_in[1];   // [K,512] fp32
  const int D = 512;
  const int M = in_sizes[0] / D;             // 16384
  const int K = in_sizes[1] / D;             // 2048
  float* out0 = (float*)d_out;               // quantized_ste [M,512]
  float* out1 = out0 + (size_t)M * D;        // loss          [M,512]
  float* out2 = out1 + (size_t)M * D;        // nn_idx (as f32) [M]
  float* out3 = out2 + M;                    // codebook copy [K,512]

  char* ws = (char*)d_ws;
  size_t off = 0;
  u16* Bpan = (u16*)(ws + off); off += (size_t)K * D * 4;     // hi+lo interleaved
  float* c2 = (float*)(ws + off); off += (size_t)K * 4;
  const int nsub = K / 64;                                    // 32
  float2* part = (float2*)(ws + off); off += (size_t)M * nsub * 8;
  u16* Apan = (u16*)(ws + off);
  const size_t need_big = off + (size_t)M * D * 4;
  const bool big = (ws_size >= need_big);

  vq_prep<<<K, 128, 0, stream>>>(CB, Bpan, c2, out3);
  const int nmt = M / 256, nnt = K / 256;
  const int nwg = nmt * nnt;                                  // 512
  if (big) {
    vq_prep<<<M, 128, 0, stream>>>(X, Apan, nullptr, nullptr);
    vq_gemm<0><<<nwg, 512, 0, stream>>>(X, Apan, Bpan, c2, part, nnt);
  } else {
    vq_gemm<1><<<nwg, 512, 0, stream>>>(X, nullptr, Bpan, c2, part, nnt);
  }
  vq_final<<<M / 4, 256, 0, stream>>>(X, CB, part, out0, out1, out2, nsub);
}